// Round 15
// baseline (1352.101 us; speedup 1.0000x reference)
//
#include <hip/hip_runtime.h>

// Fused chunked causal attention + RoPE for MI355X (gfx950).
// B=4, SLEN=4096, H=8, ZD=128, VD=256, CHUNK=1024 -> 16 chunks x 8 heads.
// fp32 in/out; fp16 MFMA 32x32x16, fp32 accum.
// Round 15: producer-consumer wave specialization. 512-thr block:
// waves 0-3 consumers (r9 compute core verbatim: swapped-QK 32x32 MFMA,
// in-reg P, defer-max softmax; acc 128 + arch <=116 regs), waves 4-7
// producers (r9/r14 staging verbatim; data+trig prefetched 1 tile ahead,
// ~64 regs, no acc). 1C+1P per SIMD = 512 regs exact. Per tile:
// B1 -> P: cvt+write buf, issue t+1 loads -> B2 -> C: compute buf.
// Consumer never waits on HBM; producer loads ride under compute.

#define NHEAD 8
#define ZDIM  128
#define VDIM  256
#define CHUNK 1024
#define QTILE 128   // q rows per block (4 consumer waves x 32)
#define KT    32    // k rows per tile

typedef _Float16 f16x8 __attribute__((ext_vector_type(8)));
typedef _Float16 f16x4 __attribute__((ext_vector_type(4)));
typedef __fp16   h16x2 __attribute__((ext_vector_type(2)));   // cvt_pkrtz return type
typedef float    f32x4  __attribute__((ext_vector_type(4)));
typedef float    f32x16 __attribute__((ext_vector_type(16)));
typedef unsigned int u32;

#define KSTRIDE 128   // halfs per K-lds row (256B rows; chunk^(row&7) XOR swizzle)
#define VSTRIDE 36    // halfs per V^T-lds row (32 + 4 pad)
#define LOG2E   1.44269504088896f
#define RTHR    11.5415603f   /* 8 nats in log2 domain: defer-max threshold */

__global__ __launch_bounds__(512, 2)
void attn_pc(const float* __restrict__ xq, const float* __restrict__ xk,
             const float* __restrict__ xv, const float* __restrict__ cosT,
             const float* __restrict__ sinT, float* __restrict__ out)
{
  __shared__ _Float16 Klds[2][KT * KSTRIDE];     // 16.0 KB
  __shared__ _Float16 Vlds[2][VDIM * VSTRIDE];   // 36.9 KB
  // total 52.9 KB; registers (8 waves x 256) pin 1 block/CU

  // XCD-grouping swizzle (bijective on [0,512))
  const int b = (int)blockIdx.x;
  const int d = (b & 7) * 64 + (b >> 3);
  const int qpair = d & 3;                       // 0..3 -> q-tiles {7-qpair, qpair}
  const int ch = d >> 2;                         // 0..127
  const int h  = ch & 7;
  const int cb = ch >> 3;

  const int tid  = threadIdx.x;
  const bool isP = tid >= 256;                   // waves 4-7 = producers
  const int w    = tid >> 6;                     // 0..7
  const int lane = tid & 63;
  const int l31  = lane & 31;
  const int hi   = lane >> 5;                    // 0/1
  const int vswz = (l31 >> 3) & 3;               // consumer V read kblk XOR
  const int kswz = l31 & 7;                      // consumer K read chunk XOR

  const size_t row0 = (size_t)cb * CHUNK;

  // producer staging mapping (256 producer threads)
  const int ptid = tid & 255;
  const int kr   = ptid >> 3;             // K row 0..31
  const int kt8  = ptid & 7;              // K chunk pair {kt8, kt8+8}
  const int vgr  = ptid >> 5;             // 0..7 -> V rows vgr*4..+3
  const int vcl  = ptid & 31;             // V base col; owns cols vcl+32j
  const int vsw2 = (vcl >> 3) & 3;
  const int kblk = vgr >> 1;
  const int inb  = (vgr & 1) * 4;

  // producer prefetch registers (1 tile ahead): K 16 + trig 16 + V 32 floats
  f32x4 pk0, pk1, pk2, pk3, pca, psa, pcb, psb;
  float e0[8], e1[8], e2[8], e3[8];

#define LOADT(ktb_)                                                          \
  do {                                                                       \
    const int krow_ = (ktb_) + kr;                                           \
    const float* kpb_ = xk + (row0 + krow_) * (size_t)(NHEAD * ZDIM) + h * ZDIM; \
    pk0 = *(const f32x4*)(kpb_ + 8 * kt8);                                   \
    pk1 = *(const f32x4*)(kpb_ + 8 * kt8 + 4);                               \
    pk2 = *(const f32x4*)(kpb_ + 8 * kt8 + 64);                              \
    pk3 = *(const f32x4*)(kpb_ + 8 * kt8 + 68);                              \
    pca = *(const f32x4*)(cosT + krow_ * (ZDIM / 2) + 4 * kt8);              \
    psa = *(const f32x4*)(sinT + krow_ * (ZDIM / 2) + 4 * kt8);              \
    pcb = *(const f32x4*)(cosT + krow_ * (ZDIM / 2) + 4 * kt8 + 32);         \
    psb = *(const f32x4*)(sinT + krow_ * (ZDIM / 2) + 4 * kt8 + 32);         \
    const int vrow_ = (ktb_) + vgr * 4;                                      \
    const float* vp_ = xv + (row0 + vrow_) * (size_t)(NHEAD * VDIM) + h * VDIM + vcl; \
    _Pragma("unroll")                                                        \
    for (int j = 0; j < 8; ++j) {                                            \
      e0[j] = vp_[32 * j];                                                   \
      e1[j] = vp_[2048 + 32 * j];                                            \
      e2[j] = vp_[4096 + 32 * j];                                            \
      e3[j] = vp_[6144 + 32 * j];                                            \
    }                                                                        \
  } while (0)

#define WRITET(bufi)                                                         \
  do {                                                                       \
    union { h16x2 h2[4]; f16x8 v; } koA, koB;                                \
    _Pragma("unroll")                                                        \
    for (int p = 0; p < 4; ++p) {                                            \
      const float xrA = (p < 2 ? pk0[2 * p] : pk1[2 * p - 4]);               \
      const float xiA = (p < 2 ? pk0[2 * p + 1] : pk1[2 * p - 3]);           \
      koA.h2[p] = __builtin_amdgcn_cvt_pkrtz(xrA * pca[p] - xiA * psa[p],    \
                                             xrA * psa[p] + xiA * pca[p]);   \
      const float xrB = (p < 2 ? pk2[2 * p] : pk3[2 * p - 4]);               \
      const float xiB = (p < 2 ? pk2[2 * p + 1] : pk3[2 * p - 3]);           \
      koB.h2[p] = __builtin_amdgcn_cvt_pkrtz(xrB * pcb[p] - xiB * psb[p],    \
                                             xrB * psb[p] + xiB * pcb[p]);   \
    }                                                                        \
    const int sw_ = kr & 7;                                                  \
    *(f16x8*)&Klds[bufi][kr * KSTRIDE + ((kt8 ^ sw_) * 8)]       = koA.v;    \
    *(f16x8*)&Klds[bufi][kr * KSTRIDE + (((kt8 + 8) ^ sw_) * 8)] = koB.v;    \
    _Pragma("unroll")                                                        \
    for (int j = 0; j < 8; ++j) {                                            \
      union { h16x2 a2[2]; f16x4 v; } t;                                     \
      t.a2[0] = __builtin_amdgcn_cvt_pkrtz(e0[j], e1[j]);                    \
      t.a2[1] = __builtin_amdgcn_cvt_pkrtz(e2[j], e3[j]);                    \
      *(f16x4*)&Vlds[bufi][(vcl + 32 * j) * VSTRIDE + ((kblk ^ vsw2) * 8) + (inb ^ ((j & 1) * 4))] = t.v; \
    }                                                                        \
  } while (0)

  for (int half = 0; half < 2; ++half) {
    const int qt = half ? qpair : (7 - qpair);   // heavy q-tile first
    const int wq0 = qt * QTILE + (w & 3) * 32;   // consumer q-base
    const int qgr = wq0 + l31;
    const int nkt = 4 * (qt + 1);

    f16x8 qfrag[8];
    f32x16 acc[8];
    float mrun = -1e30f;
    float lrun = 0.f;

    if (isP) {
      LOADT(0);   // tile 0 loads in flight while consumers prep Q
    } else {
      // ---- Q -> registers as 32x32x16 B-frags (RoPE'd, pre-scaled by log2e) ----
      const float* qp = xq + (row0 + qgr) * (size_t)(NHEAD * ZDIM) + h * ZDIM;
      const float* cq = cosT + qgr * (ZDIM / 2);
      const float* sq = sinT + qgr * (ZDIM / 2);
#pragma unroll
      for (int dblk = 0; dblk < 8; ++dblk) {
        const int d0 = dblk * 16 + hi * 8;
        f32x4 a  = *(const f32x4*)(qp + d0);
        f32x4 b2 = *(const f32x4*)(qp + d0 + 4);
        f32x4 cv = *(const f32x4*)(cq + (d0 >> 1));
        f32x4 sv = *(const f32x4*)(sq + (d0 >> 1));
        union { h16x2 h2[4]; f16x8 v; } fr;
#pragma unroll
        for (int p = 0; p < 4; ++p) {
          const float xr = (p < 2 ? a[2 * p] : b2[2 * p - 4]);
          const float xi = (p < 2 ? a[2 * p + 1] : b2[2 * p - 3]);
          fr.h2[p] = __builtin_amdgcn_cvt_pkrtz((xr * cv[p] - xi * sv[p]) * LOG2E,
                                                (xr * sv[p] + xi * cv[p]) * LOG2E);
        }
        qfrag[dblk] = fr.v;
      }
      const f32x16 zf = {};
#pragma unroll
      for (int g = 0; g < 8; ++g) acc[g] = zf;
    }

    int buf = 0;
    for (int kt = 0; kt < nkt; ++kt) {
      const int ktb = kt * KT;

      __syncthreads();   // B1: consumers done reading buf (tile kt-2)
      if (isP) {
        WRITET(buf);                          // regs loaded one tile ago
        if (kt + 1 < nkt) LOADT(ktb + KT);    // in flight under compute(kt)
      }
      __syncthreads();   // B2: tile kt staged and visible

      if (!isP && ktb <= wq0 + 31) {
        // ---- S^T = K Q : col=l31=q, row=k-local ----
        f32x16 s = {};
        __builtin_amdgcn_s_setprio(1);
#pragma unroll
        for (int dblk = 0; dblk < 8; ++dblk) {
          f16x8 kf = *(const f16x8*)&Klds[buf][l31 * KSTRIDE + (((dblk * 2 + hi) ^ kswz) * 8)];
          s = __builtin_amdgcn_mfma_f32_32x32x16_f16(kf, qfrag[dblk], s, 0, 0, 0);
        }
        __builtin_amdgcn_s_setprio(0);

        // ---- causal mask (partial tiles only); k_local = (r&3)+8*(r>>2)+4*hi ----
        if (ktb + 31 > wq0) {
#pragma unroll
          for (int r = 0; r < 16; ++r) {
            const int kg = ktb + ((r & 3) + 8 * (r >> 2) + 4 * hi);
            if (kg > qgr) s[r] = -1.0e9f;
          }
        }

        // ---- softmax: lane-local max + one cross-half shuffle ----
        float m = s[0];
#pragma unroll
        for (int r = 1; r < 16; ++r) m = fmaxf(m, s[r]);
        m = fmaxf(m, __shfl_xor(m, 32));
        const bool need = (m > mrun + RTHR);
        if (__any(need)) {
          const float Mn = fmaxf(mrun, m);
          const float al = exp2f(mrun - Mn);
          mrun = Mn;
          lrun *= al;
#pragma unroll
          for (int r = 0; r < 16; ++r) {
            const float alr = __shfl(al, (r & 3) + 8 * (r >> 2) + 4 * hi);
#pragma unroll
            for (int g = 0; g < 8; ++g) acc[g][r] *= alr;
          }
        }
        float lsum = 0.f;
#pragma unroll
        for (int r = 0; r < 16; ++r) {
          s[r] = exp2f(s[r] - mrun);
          lsum += s[r];
        }
        lrun += lsum;

        // ---- P -> fp16 A-frags in registers, then PV ----
#pragma unroll
        for (int kb = 0; kb < 2; ++kb) {
          union { h16x2 h; u32 u; } A_, B_, C_, D_;
          A_.h = __builtin_amdgcn_cvt_pkrtz(s[8 * kb + 0], s[8 * kb + 1]);
          B_.h = __builtin_amdgcn_cvt_pkrtz(s[8 * kb + 2], s[8 * kb + 3]);
          C_.h = __builtin_amdgcn_cvt_pkrtz(s[8 * kb + 4], s[8 * kb + 5]);
          D_.h = __builtin_amdgcn_cvt_pkrtz(s[8 * kb + 6], s[8 * kb + 7]);
          const u32 G1 = hi ? A_.u : C_.u;
          const u32 G2 = hi ? B_.u : D_.u;
          const u32 G1s = (u32)__shfl_xor((int)G1, 32);
          const u32 G2s = (u32)__shfl_xor((int)G2, 32);
          union { u32 u[4]; f16x8 v; } af;
          af.u[0] = hi ? G1s : A_.u;
          af.u[1] = hi ? G2s : B_.u;
          af.u[2] = hi ? C_.u : G1s;
          af.u[3] = hi ? D_.u : G2s;
          __builtin_amdgcn_s_setprio(1);
#pragma unroll
          for (int g = 0; g < 8; ++g) {
            const int vcol = g * 32 + l31;
            const int ck = (((kb * 2 + hi) ^ vswz) * 8);
            const int fl = (g & 1) * 4;   // matches write-side (col>>5)&1 = j&1
            union { f16x4 h4[2]; f16x8 v; } bf;
            bf.h4[0] = *(const f16x4*)&Vlds[buf][vcol * VSTRIDE + ck + fl];
            bf.h4[1] = *(const f16x4*)&Vlds[buf][vcol * VSTRIDE + ck + (fl ^ 4)];
            acc[g] = __builtin_amdgcn_mfma_f32_32x32x16_f16(af.v, bf.v, acc[g], 0, 0, 0);
          }
          __builtin_amdgcn_s_setprio(0);
        }
      }
      buf ^= 1;
    }

    // ---- epilogue (consumers only) ----
    if (!isP) {
      const float ls = lrun + __shfl_xor(lrun, 32);
      const float linv = 1.0f / ls;
#pragma unroll
      for (int r = 0; r < 16; ++r) {
        const int qloc = (r & 3) + 8 * (r >> 2) + 4 * hi;
        const float lr = __shfl(linv, qloc);
        const size_t ob = (row0 + wq0 + qloc) * (size_t)(NHEAD * VDIM) + h * VDIM + l31;
#pragma unroll
        for (int g = 0; g < 8; ++g)
          out[ob + g * 32] = acc[g][r] * lr;
      }
    }
  }
#undef LOADT
#undef WRITET
}

extern "C" void kernel_launch(void* const* d_in, const int* in_sizes, int n_in,
                              void* d_out, int out_size, void* d_ws, size_t ws_size,
                              hipStream_t stream) {
  const float* xq   = (const float*)d_in[0];
  const float* xk   = (const float*)d_in[1];
  const float* xv   = (const float*)d_in[2];
  // d_in[3] = mask (unused: causal mask computed analytically)
  const float* cosT = (const float*)d_in[4];
  const float* sinT = (const float*)d_in[5];
  float* out = (float*)d_out;

  dim3 grid(512);    // (4 qpairs) x (128 chunk*head), XCD-swizzled
  dim3 block(512);   // 4 consumer waves + 4 producer waves
  attn_pc<<<grid, block, 0, stream>>>(xq, xk, xv, cosT, sinT, out);
}